// Round 18
// baseline (244.980 us; speedup 1.0000x reference)
//
#include <hip/hip_runtime.h>
#include <hip/hip_bf16.h>

typedef unsigned short u16;
typedef unsigned int   u32;
typedef __attribute__((ext_vector_type(8))) short short8;
typedef __attribute__((ext_vector_type(4))) float f32x4;
typedef _Float16 half2v __attribute__((ext_vector_type(2)));

#define NN 4096        // nodes
#define NE 262144      // edges
#define EMB 256
#define NH 4
#define HD 64

__device__ __forceinline__ float4 load4f(const float* p) { return *reinterpret_cast<const float4*>(p); }
__device__ __forceinline__ float sanitize_f(float v) {
  v = (v != v) ? 0.f : v;                 // nan -> 0
  return fminf(fmaxf(v, -1000.f), 1000.f); // +-inf and clip -> +-1000
}
__device__ __forceinline__ u16 f2b_rne(float x) {          // f32 -> bf16 bits, round-nearest-even
  u32 b = __float_as_uint(x);
  b += 0x7fff + ((b >> 16) & 1);
  return (u16)(b >> 16);
}
__device__ __forceinline__ u32 pack2(float a, float b) {
  return (u32)f2b_rne(a) | ((u32)f2b_rne(b) << 16);
}
__device__ __forceinline__ float b2f(u16 u) { return __uint_as_float((u32)u << 16); }
__device__ __forceinline__ u16 f2h(float x) {              // f32 -> f16 bits (rte)
  _Float16 h = (_Float16)x;
  return *reinterpret_cast<u16*>(&h);
}

// ================= generic MFMA GEMM: out = act(A[M,K] @ W^T + bias) =================
struct GTile {
  const float* A;     // input rows [M][K]
  const float* W;     // 64 weight rows for this tile: [64][K]
  const float* bias;  // 64 entries
  float*       out;
  int          colOff;
  int          ldOut;
  int          obf16; // 0 f32 | 1 bf16 | 2 bf16-TRANSPOSED out[col*ld+row] | 3 f16
};
struct GArgs { GTile t[32]; };

template<int ACT>   // 0 none, 1 sanitize, 2 lrelu(0.2)
__global__ __launch_bounds__(256) void gemm_mfma(const GArgs ga, int K) {
  __shared__ short As[64 * 40];
  __shared__ short Bs[64 * 40];
  const int t = threadIdx.x;
  const int bm = blockIdx.x * 64;
  const GTile tl = ga.t[blockIdx.y];
  const int w = t >> 6, l = t & 63, g = l >> 4, r16 = l & 15;
  const int wr = w >> 1, wc = w & 1;
  const int lrow = t >> 2, lseg = (t & 3) * 8;

  const float* Ap = tl.A + (size_t)(bm + lrow) * K + lseg;
  const float* Wp = tl.W + (size_t)lrow * K + lseg;

  f32x4 acc[2][2] = {{{0.f,0.f,0.f,0.f},{0.f,0.f,0.f,0.f}},{{0.f,0.f,0.f,0.f},{0.f,0.f,0.f,0.f}}};
  for (int k0 = 0; k0 < K; k0 += 32) {
    float4 a0 = load4f(Ap + k0), a1 = load4f(Ap + k0 + 4);
    float4 b0 = load4f(Wp + k0), b1 = load4f(Wp + k0 + 4);
    __syncthreads();
    *(uint4*)&As[lrow * 40 + lseg] =
        make_uint4(pack2(a0.x,a0.y), pack2(a0.z,a0.w), pack2(a1.x,a1.y), pack2(a1.z,a1.w));
    *(uint4*)&Bs[lrow * 40 + lseg] =
        make_uint4(pack2(b0.x,b0.y), pack2(b0.z,b0.w), pack2(b1.x,b1.y), pack2(b1.z,b1.w));
    __syncthreads();
    short8 af0 = *(const short8*)&As[(wr*32 +      r16) * 40 + 8*g];
    short8 af1 = *(const short8*)&As[(wr*32 + 16 + r16) * 40 + 8*g];
    short8 bf0 = *(const short8*)&Bs[(wc*32 +      r16) * 40 + 8*g];
    short8 bf1 = *(const short8*)&Bs[(wc*32 + 16 + r16) * 40 + 8*g];
    acc[0][0] = __builtin_amdgcn_mfma_f32_16x16x32_bf16(af0, bf0, acc[0][0], 0, 0, 0);
    acc[0][1] = __builtin_amdgcn_mfma_f32_16x16x32_bf16(af0, bf1, acc[0][1], 0, 0, 0);
    acc[1][0] = __builtin_amdgcn_mfma_f32_16x16x32_bf16(af1, bf0, acc[1][0], 0, 0, 0);
    acc[1][1] = __builtin_amdgcn_mfma_f32_16x16x32_bf16(af1, bf1, acc[1][1], 0, 0, 0);
  }
  const float bj[2] = { tl.bias[wc*32 + r16], tl.bias[wc*32 + 16 + r16] };
#pragma unroll
  for (int i = 0; i < 2; i++) {
#pragma unroll
    for (int j = 0; j < 2; j++) {
      int col  = tl.colOff + wc*32 + 16*j + r16;
      int row0 = bm + wr*32 + 16*i + 4*g;
      if (tl.obf16 == 2) {
        u16 pk[4];
#pragma unroll
        for (int r = 0; r < 4; r++) pk[r] = f2b_rne(acc[i][j][r] + bj[j]);
        *(uint2*)((u16*)tl.out + (size_t)col * tl.ldOut + row0) = *(uint2*)pk;
      } else {
#pragma unroll
        for (int r = 0; r < 4; r++) {
          float v = acc[i][j][r] + bj[j];
          if (ACT == 1) v = sanitize_f(v);
          if (ACT == 2) v = (v > 0.f) ? v : 0.2f * v;
          if (tl.obf16 == 1)      ((u16*)tl.out)[(size_t)(row0 + r) * tl.ldOut + col] = f2b_rne(v);
          else if (tl.obf16 == 3) ((u16*)tl.out)[(size_t)(row0 + r) * tl.ldOut + col] = f2h(v);
          else                    tl.out[(size_t)(row0 + r) * tl.ldOut + col] = v;
        }
      }
    }
  }
}

// ---------------- img GEMM split-K: K=2048 over 4 z-blocks of 512 ----------------
__global__ __launch_bounds__(256) void gemm_img_splitk(const float* __restrict__ A, const float* __restrict__ W,
                                                       float* __restrict__ part) {
  __shared__ short As[64 * 40];
  __shared__ short Bs[64 * 40];
  const int t = threadIdx.x;
  const int bm = blockIdx.x * 64, bn = blockIdx.y * 64, ks = blockIdx.z;
  const int w = t >> 6, l = t & 63, g = l >> 4, r16 = l & 15;
  const int wr = w >> 1, wc = w & 1;
  const int lrow = t >> 2, lseg = (t & 3) * 8;

  const float* Ap = A + (size_t)(bm + lrow) * 2048 + ks * 512 + lseg;
  const float* Wp = W + (size_t)(bn + lrow) * 2048 + ks * 512 + lseg;

  f32x4 acc[2][2] = {{{0.f,0.f,0.f,0.f},{0.f,0.f,0.f,0.f}},{{0.f,0.f,0.f,0.f},{0.f,0.f,0.f,0.f}}};
  for (int k0 = 0; k0 < 512; k0 += 32) {
    float4 a0 = load4f(Ap + k0), a1 = load4f(Ap + k0 + 4);
    float4 b0 = load4f(Wp + k0), b1 = load4f(Wp + k0 + 4);
    __syncthreads();
    *(uint4*)&As[lrow * 40 + lseg] =
        make_uint4(pack2(a0.x,a0.y), pack2(a0.z,a0.w), pack2(a1.x,a1.y), pack2(a1.z,a1.w));
    *(uint4*)&Bs[lrow * 40 + lseg] =
        make_uint4(pack2(b0.x,b0.y), pack2(b0.z,b0.w), pack2(b1.x,b1.y), pack2(b1.z,b1.w));
    __syncthreads();
    short8 af0 = *(const short8*)&As[(wr*32 +      r16) * 40 + 8*g];
    short8 af1 = *(const short8*)&As[(wr*32 + 16 + r16) * 40 + 8*g];
    short8 bf0 = *(const short8*)&Bs[(wc*32 +      r16) * 40 + 8*g];
    short8 bf1 = *(const short8*)&Bs[(wc*32 + 16 + r16) * 40 + 8*g];
    acc[0][0] = __builtin_amdgcn_mfma_f32_16x16x32_bf16(af0, bf0, acc[0][0], 0, 0, 0);
    acc[0][1] = __builtin_amdgcn_mfma_f32_16x16x32_bf16(af0, bf1, acc[0][1], 0, 0, 0);
    acc[1][0] = __builtin_amdgcn_mfma_f32_16x16x32_bf16(af1, bf0, acc[1][0], 0, 0, 0);
    acc[1][1] = __builtin_amdgcn_mfma_f32_16x16x32_bf16(af1, bf1, acc[1][1], 0, 0, 0);
  }
  float* op = part + (size_t)ks * (NN * 256);
#pragma unroll
  for (int i = 0; i < 2; i++) {
#pragma unroll
    for (int j = 0; j < 2; j++) {
      int col = bn + wc*32 + 16*j + r16;
#pragma unroll
      for (int r = 0; r < 4; r++) {
        int row = bm + wr*32 + 16*i + 4*g + r;
        op[(size_t)row * 256 + col] = acc[i][j][r];
      }
    }
  }
}
__global__ __launch_bounds__(256) void gemm_img_reduce(const float* __restrict__ part,
                                                       const float* __restrict__ bias,
                                                       float* __restrict__ h) {
  int idx = blockIdx.x * 256 + threadIdx.x;
  int row = idx >> 6, c4 = (idx & 63) * 4;
  size_t o = (size_t)row * 256 + c4;
  float4 s = load4f(part + o);
  float4 p1 = load4f(part + 1048576 + o);
  float4 p2 = load4f(part + 2097152 + o);
  float4 p3 = load4f(part + 3145728 + o);
  float4 bb = load4f(bias + c4);
  s.x += p1.x + p2.x + p3.x + bb.x;
  s.y += p1.y + p2.y + p3.y + bb.y;
  s.z += p1.z + p2.z + p3.z + bb.z;
  s.w += p1.w + p2.w + p3.w + bb.w;
  *(float4*)&h[o] = s;
}

// ---------------- causal MHA v4: 64-q blocks, LDS-shared K/V, pipelined, split-K x4 ----------------
#define KSTR 72
__global__ __launch_bounds__(256, 4) void mha_mfma3(const u16* __restrict__ qkb, const u16* __restrict__ vtb,
                                                    float* __restrict__ Opart, float* __restrict__ mspart) {
  __shared__ u16 Ks[64 * KSTR];
  __shared__ u16 Vs[64 * KSTR];
  const int bid = blockIdx.x;
  const int ks  = bid & 3;
  const int hh  = (bid >> 2) & 3;
  const int T   = 63 - (bid >> 4);
  const int q0  = T * 64;
  const int t   = threadIdx.x;
  const int w   = t >> 6, l = t & 63, g = l >> 4, r16 = l & 15;
  const int hofs = hh * 64;
  const int lrow = t >> 3, lc8 = (t & 7) * 8;

  const u16* qrow = qkb + (size_t)(q0 + 16 * w + r16) * 512 + hofs;
  short8 Qf0 = *(const short8*)&qrow[8 * g];
  short8 Qf1 = *(const short8*)&qrow[32 + 8 * g];

  f32x4 O0 = {0.f,0.f,0.f,0.f}, O1 = O0, O2 = O0, O3 = O0;
  float m = -INFINITY, ssum = 0.f;

  uint4 rk0, rk1, rv0, rv1;
  if (ks <= T) {
    int k0 = ks * 64;
    rk0 = *(const uint4*)&qkb[(size_t)(k0 + lrow) * 512 + 256 + hofs + lc8];
    rk1 = *(const uint4*)&qkb[(size_t)(k0 + 32 + lrow) * 512 + 256 + hofs + lc8];
    rv0 = *(const uint4*)&vtb[(size_t)(hofs + lrow) * 4096 + k0 + lc8];
    rv1 = *(const uint4*)&vtb[(size_t)(hofs + 32 + lrow) * 4096 + k0 + lc8];
  }
  for (int kt = ks; kt <= T; kt += 4) {
    __syncthreads();
    *(uint4*)&Ks[lrow * KSTR + lc8]        = rk0;
    *(uint4*)&Ks[(32 + lrow) * KSTR + lc8] = rk1;
    *(uint4*)&Vs[lrow * KSTR + lc8]        = rv0;
    *(uint4*)&Vs[(32 + lrow) * KSTR + lc8] = rv1;
    __syncthreads();
    if (kt + 4 <= T) {
      int k2 = (kt + 4) * 64;
      rk0 = *(const uint4*)&qkb[(size_t)(k2 + lrow) * 512 + 256 + hofs + lc8];
      rk1 = *(const uint4*)&qkb[(size_t)(k2 + 32 + lrow) * 512 + 256 + hofs + lc8];
      rv0 = *(const uint4*)&vtb[(size_t)(hofs + lrow) * 4096 + k2 + lc8];
      rv1 = *(const uint4*)&vtb[(size_t)(hofs + 32 + lrow) * 4096 + k2 + lc8];
    }
    f32x4 S0 = {0.f,0.f,0.f,0.f}, S1 = S0, S2 = S0, S3 = S0;
    {
      short8 a0 = *(const short8*)&Ks[(r16)      * KSTR + 8*g];
      short8 a1 = *(const short8*)&Ks[(16 + r16) * KSTR + 8*g];
      short8 a2 = *(const short8*)&Ks[(32 + r16) * KSTR + 8*g];
      short8 a3 = *(const short8*)&Ks[(48 + r16) * KSTR + 8*g];
      S0 = __builtin_amdgcn_mfma_f32_16x16x32_bf16(a0, Qf0, S0, 0, 0, 0);
      S1 = __builtin_amdgcn_mfma_f32_16x16x32_bf16(a1, Qf0, S1, 0, 0, 0);
      S2 = __builtin_amdgcn_mfma_f32_16x16x32_bf16(a2, Qf0, S2, 0, 0, 0);
      S3 = __builtin_amdgcn_mfma_f32_16x16x32_bf16(a3, Qf0, S3, 0, 0, 0);
      short8 b0 = *(const short8*)&Ks[(r16)      * KSTR + 32 + 8*g];
      short8 b1 = *(const short8*)&Ks[(16 + r16) * KSTR + 32 + 8*g];
      short8 b2 = *(const short8*)&Ks[(32 + r16) * KSTR + 32 + 8*g];
      short8 b3 = *(const short8*)&Ks[(48 + r16) * KSTR + 32 + 8*g];
      S0 = __builtin_amdgcn_mfma_f32_16x16x32_bf16(b0, Qf1, S0, 0, 0, 0);
      S1 = __builtin_amdgcn_mfma_f32_16x16x32_bf16(b1, Qf1, S1, 0, 0, 0);
      S2 = __builtin_amdgcn_mfma_f32_16x16x32_bf16(b2, Qf1, S2, 0, 0, 0);
      S3 = __builtin_amdgcn_mfma_f32_16x16x32_bf16(b3, Qf1, S3, 0, 0, 0);
    }
    float sc[4][4];
#pragma unroll
    for (int r = 0; r < 4; r++) {
      sc[0][r] = S0[r] * 0.125f; sc[1][r] = S1[r] * 0.125f;
      sc[2][r] = S2[r] * 0.125f; sc[3][r] = S3[r] * 0.125f;
    }
    if (kt == T) {
#pragma unroll
      for (int mb = 0; mb < 4; mb++)
#pragma unroll
        for (int r = 0; r < 4; r++)
          if (16 * mb + 4 * g + r > 16 * w + r16) sc[mb][r] = -INFINITY;
    }
    float tm = sc[0][0];
#pragma unroll
    for (int mb = 0; mb < 4; mb++)
#pragma unroll
      for (int r = 0; r < 4; r++) tm = fmaxf(tm, sc[mb][r]);
    tm = fmaxf(tm, __shfl_xor(tm, 16));
    tm = fmaxf(tm, __shfl_xor(tm, 32));
    float mn = fmaxf(m, tm);
    float ef = __expf(m - mn);
    float pv[4][4];
    float ps = 0.f;
#pragma unroll
    for (int mb = 0; mb < 4; mb++)
#pragma unroll
      for (int r = 0; r < 4; r++) { pv[mb][r] = __expf(sc[mb][r] - mn); ps += pv[mb][r]; }
    ps += __shfl_xor(ps, 16);
    ps += __shfl_xor(ps, 32);
    ssum = ssum * ef + ps;
    m = mn;
#pragma unroll
    for (int r = 0; r < 4; r++) {
      float efr = __shfl(ef, 4 * g + r);
      O0[r] *= efr; O1[r] *= efr; O2[r] *= efr; O3[r] *= efr;
    }
    u32 pk[2][4];
#pragma unroll
    for (int c = 0; c < 2; c++)
#pragma unroll
      for (int rs = 0; rs < 4; rs++) pk[c][rs] = pack2(pv[2 * c][rs], pv[2 * c + 1][rs]);
    short8 ap[2];
#pragma unroll
    for (int c = 0; c < 2; c++) {
#pragma unroll
      for (int jb = 0; jb < 2; jb++) {
        int x = 2 * g + jb;
        int hi = x >> 2;
        int src = r16 + 16 * (x & 3);
#pragma unroll
        for (int rs = 0; rs < 4; rs++) {
          u32 v = __shfl(pk[c][rs], src);
          ap[c][jb * 4 + rs] = (short)(hi ? (v >> 16) : (v & 0xffff));
        }
      }
    }
    {
      short8 V00 = *(const short8*)&Vs[(r16)      * KSTR + 8*g];
      short8 V10 = *(const short8*)&Vs[(16 + r16) * KSTR + 8*g];
      short8 V20 = *(const short8*)&Vs[(32 + r16) * KSTR + 8*g];
      short8 V30 = *(const short8*)&Vs[(48 + r16) * KSTR + 8*g];
      O0 = __builtin_amdgcn_mfma_f32_16x16x32_bf16(ap[0], V00, O0, 0, 0, 0);
      O1 = __builtin_amdgcn_mfma_f32_16x16x32_bf16(ap[0], V10, O1, 0, 0, 0);
      O2 = __builtin_amdgcn_mfma_f32_16x16x32_bf16(ap[0], V20, O2, 0, 0, 0);
      O3 = __builtin_amdgcn_mfma_f32_16x16x32_bf16(ap[0], V30, O3, 0, 0, 0);
      short8 V01 = *(const short8*)&Vs[(r16)      * KSTR + 32 + 8*g];
      short8 V11 = *(const short8*)&Vs[(16 + r16) * KSTR + 32 + 8*g];
      short8 V21 = *(const short8*)&Vs[(32 + r16) * KSTR + 32 + 8*g];
      short8 V31 = *(const short8*)&Vs[(48 + r16) * KSTR + 32 + 8*g];
      O0 = __builtin_amdgcn_mfma_f32_16x16x32_bf16(ap[1], V01, O0, 0, 0, 0);
      O1 = __builtin_amdgcn_mfma_f32_16x16x32_bf16(ap[1], V11, O1, 0, 0, 0);
      O2 = __builtin_amdgcn_mfma_f32_16x16x32_bf16(ap[1], V21, O2, 0, 0, 0);
      O3 = __builtin_amdgcn_mfma_f32_16x16x32_bf16(ap[1], V31, O3, 0, 0, 0);
    }
  }

  size_t ob = (size_t)bid * 4096;
#pragma unroll
  for (int r = 0; r < 4; r++) {
    int q = 16 * w + 4 * g + r;
    Opart[ob + q * 64 + r16]      = O0[r];
    Opart[ob + q * 64 + 16 + r16] = O1[r];
    Opart[ob + q * 64 + 32 + r16] = O2[r];
    Opart[ob + q * 64 + 48 + r16] = O3[r];
  }
  if (l < 16) {
    mspart[bid * 128 + 16 * w + l]      = m;
    mspart[bid * 128 + 64 + 16 * w + l] = ssum;
  }
}

// merge 4 stripe-partials -> normalized output. grid 256: T = mb>>2, h = mb&3.
__global__ __launch_bounds__(256) void mha_merge3(const float* __restrict__ Opart, const float* __restrict__ mspart,
                                                  float* __restrict__ out) {
  int mb = blockIdx.x;
  int h = mb & 3, T = mb >> 2;
  int bid0 = ((63 - T) << 4) | (h << 2);
  int t = threadIdx.x;
  int q = t >> 2, dbase = (t & 3) * 16;
  float mm[4], ss[4];
#pragma unroll
  for (int i = 0; i < 4; i++) {
    mm[i] = mspart[(bid0 + i) * 128 + q];
    ss[i] = mspart[(bid0 + i) * 128 + 64 + q];
  }
  float M = fmaxf(fmaxf(mm[0], mm[1]), fmaxf(mm[2], mm[3]));
  float e[4];
  float S = 0.f;
#pragma unroll
  for (int i = 0; i < 4; i++) {
    e[i] = (mm[i] == -INFINITY) ? 0.f : __expf(mm[i] - M);
    S += e[i] * ss[i];
  }
  float inv = 1.f / S;
  float* Y = out + (size_t)(T * 64 + q) * EMB + h * 64 + dbase;
#pragma unroll
  for (int i = 0; i < 4; i++) {
    float4 a0 = load4f(Opart + (size_t)(bid0 + 0) * 4096 + q * 64 + dbase + 4 * i);
    float4 a1 = load4f(Opart + (size_t)(bid0 + 1) * 4096 + q * 64 + dbase + 4 * i);
    float4 a2 = load4f(Opart + (size_t)(bid0 + 2) * 4096 + q * 64 + dbase + 4 * i);
    float4 a3 = load4f(Opart + (size_t)(bid0 + 3) * 4096 + q * 64 + dbase + 4 * i);
    float4 r;
    r.x = (e[0]*a0.x + e[1]*a1.x + e[2]*a2.x + e[3]*a3.x) * inv;
    r.y = (e[0]*a0.y + e[1]*a1.y + e[2]*a2.y + e[3]*a3.y) * inv;
    r.z = (e[0]*a0.z + e[1]*a1.z + e[2]*a2.z + e[3]*a3.z) * inv;
    r.w = (e[0]*a0.w + e[1]*a1.w + e[2]*a2.w + e[3]*a3.w) * inv;
    *(float4*)(Y + 4 * i) = r;
  }
}

// ---------------- CSR build ----------------
__global__ void zero_i32(int* p, int n) {
  int i = blockIdx.x * 256 + threadIdx.x;
  if (i < n) p[i] = 0;
}
__global__ void hist_dst(const int* __restrict__ adj, int* __restrict__ cnt) {
  int e = blockIdx.x * 256 + threadIdx.x;
  if (e < NE) atomicAdd(&cnt[adj[NE + e]], 1);
}
__global__ __launch_bounds__(1024) void scan4096(const int* __restrict__ cnt, int* __restrict__ indptr,
                                                 int* __restrict__ cursor) {
  int t = threadIdx.x;
  int4 c = *reinterpret_cast<const int4*>(cnt + t * 4);
  int s0 = c.x, s1 = s0 + c.y, s2 = s1 + c.z, s3 = s2 + c.w;
  int lane = t & 63, w = t >> 6;
  int x = s3;
#pragma unroll
  for (int off = 1; off < 64; off <<= 1) {
    int y = __shfl_up(x, off);
    if (lane >= off) x += y;
  }
  __shared__ int wsum[16];
  if (lane == 63) wsum[w] = x;
  __syncthreads();
  if (t == 0) {
    int acc = 0;
    for (int i = 0; i < 16; i++) { int tv = wsum[i]; wsum[i] = acc; acc += tv; }
  }
  __syncthreads();
  int b = wsum[w] + x - s3;
  indptr[t*4+0] = b;      indptr[t*4+1] = b + s0;
  indptr[t*4+2] = b + s1; indptr[t*4+3] = b + s2;
  cursor[t*4+0] = b;      cursor[t*4+1] = b + s0;
  cursor[t*4+2] = b + s1; cursor[t*4+3] = b + s2;
  if (t == 1023) indptr[4096] = b + s3;
}
__global__ void scatter_edges(const int* __restrict__ adj, int* __restrict__ cursor, int* __restrict__ esrc) {
  int e = blockIdx.x * 256 + threadIdx.x;
  if (e < NE) {
    int dst = adj[NE + e];
    int pos = atomicAdd(&cursor[dst], 1);
    esrc[pos] = adj[e];
  }
}

// ---------------- TransformerConv aggregation v3: WAVE-AUTONOMOUS (no barriers) ----------------
// grid 8192 x 4 waves = 32768 waves; wave gw handles path=gw>>14, node=(gw>>2)&4095, head=gw&3.
// All LDS regions are per-wave -> same-wave RAW only (compiler-ordered), no __syncthreads.
__global__ __launch_bounds__(256, 4) void conv_agg3(const float* __restrict__ qbO, const float* __restrict__ qbA,
                                                    const u16* __restrict__ kbO, const u16* __restrict__ kbA,
                                                    const u16* __restrict__ vbO, const u16* __restrict__ vbA,
                                                    const int* __restrict__ indptr, const int* __restrict__ esrc,
                                                    float* __restrict__ yO, float* __restrict__ yA) {
  __shared__ float sc_s[4][64];
  __shared__ float p_s[4][64];
  __shared__ int   s_s[4][64];
  int w = threadIdx.x >> 6, lane = threadIdx.x & 63;
  int gw = blockIdx.x * 4 + w;
  int path = gw >> 14;
  int n = (gw >> 2) & 4095;
  int h = gw & 3;
  const float* qb = path ? qbA : qbO;
  const u16*   kb = path ? kbA : kbO;
  const u16*   vb = path ? vbA : vbO;
  float*       y  = path ? yA  : yO;
  int lr8 = lane >> 3;
  int lseg = (lane & 7) * 8;
  // q for this head: each lane needs dims lseg..lseg+7 (f16, scale folded). Load via coalesced
  // read of own dim then redistribute with shfl (dim j lives in lane j).
  float qown = qb[(size_t)n * EMB + h * HD + lane] * 0.125f;
  half2v qp[4];
#pragma unroll
  for (int j = 0; j < 4; j++) {
    qp[j][0] = (_Float16)__shfl(qown, lseg + 2*j);
    qp[j][1] = (_Float16)__shfl(qown, lseg + 2*j + 1);
  }
  int start = indptr[n], end = indptr[n + 1];
  float m = -INFINITY, s = 0.f;
  float o0 = 0.f, o1 = 0.f, o2 = 0.f, o3 = 0.f;
  for (int p0 = start; p0 < end; p0 += 64) {
    int nk = end - p0; if (nk > 64) nk = 64;
    s_s[w][lane] = (lane < nk) ? esrc[p0 + lane] : 0;   // per-wave staging, same-wave RAW
#pragma unroll
    for (int pass = 0; pass < 8; pass++) {
      int row = pass * 8 + lr8;
      int src = s_s[w][row];
      uint4 k4 = *(const uint4*)&kb[(size_t)src * EMB + h * HD + lseg];
      float acc = __builtin_amdgcn_fdot2(*(half2v*)&k4.x, qp[0],
                  __builtin_amdgcn_fdot2(*(half2v*)&k4.y, qp[1],
                  __builtin_amdgcn_fdot2(*(half2v*)&k4.z, qp[2],
                  __builtin_amdgcn_fdot2(*(half2v*)&k4.w, qp[3], 0.f, false), false), false), false);
      acc += __shfl_xor(acc, 1);
      acc += __shfl_xor(acc, 2);
      acc += __shfl_xor(acc, 4);
      if ((lane & 7) == 0) sc_s[w][row] = (row < nk) ? acc : -INFINITY;
    }
    float sc = sc_s[w][lane];
    float bm = sc;
#pragma unroll
    for (int off = 32; off; off >>= 1) bm = fmaxf(bm, __shfl_xor(bm, off));
    float mn = fmaxf(m, bm);
    float ef = __expf(m - mn);
    float p = __expf(sc - mn);
    float ps = p;
#pragma unroll
    for (int off = 32; off; off >>= 1) ps += __shfl_xor(ps, off);
    s = s * ef + ps;
    m = mn;
    o0 *= ef; o1 *= ef; o2 *= ef; o3 *= ef;
    p_s[w][lane] = p;
    const u16* vcol = vb + h * HD + lane;
    int nk4 = (nk + 3) & ~3;
    for (int jj = 0; jj < nk4; jj += 4) {
      int sa  = __builtin_amdgcn_readfirstlane(s_s[w][jj]);
      int sb  = __builtin_amdgcn_readfirstlane(s_s[w][jj+1]);
      int scx = __builtin_amdgcn_readfirstlane(s_s[w][jj+2]);
      int sd  = __builtin_amdgcn_readfirstlane(s_s[w][jj+3]);
      float pa = p_s[w][jj],   pb = p_s[w][jj+1];
      float pc = p_s[w][jj+2], pd = p_s[w][jj+3];
      o0 = fmaf(pa, b2f(vcol[(size_t)sa  * EMB]), o0);
      o1 = fmaf(pb, b2f(vcol[(size_t)sb  * EMB]), o1);
      o2 = fmaf(pc, b2f(vcol[(size_t)scx * EMB]), o2);
      o3 = fmaf(pd, b2f(vcol[(size_t)sd  * EMB]), o3);
    }
  }
  float o = (o0 + o1) + (o2 + o3);
  float agg = o / (s + 1e-16f);
  y[(size_t)n * EMB + h * HD + lane] += agg;
}

// ---------------- instance norm (both paths) ----------------
__global__ __launch_bounds__(256) void colstats_partial2(const float* __restrict__ yO, const float* __restrict__ yA,
                                                         float* __restrict__ part) {
  int bid = blockIdx.x;              // 64: path = bid>>5, pb = bid&31
  int path = bid >> 5, pb = bid & 31;
  const float* y = path ? yA : yO;
  int c = threadIdx.x;
  int r0 = pb * 128;
  float s = 0.f, q = 0.f;
  for (int r = r0; r < r0 + 128; r++) {
    float v = y[(size_t)r * EMB + c];
    s += v; q = fmaf(v, v, q);
  }
  part[(size_t)path * 16384 + pb * 512 + c] = s;
  part[(size_t)path * 16384 + pb * 512 + 256 + c] = q;
}
__global__ __launch_bounds__(256) void norm_apply2(const float* __restrict__ yO, const float* __restrict__ yA,
                                                   const float* __restrict__ part, float* __restrict__ f) {
  int bid = blockIdx.x;              // 512: path = bid>>8, rb = bid&255
  int path = bid >> 8, rb = bid & 255;
  const float* y = path ? yA : yO;
  const float* pp = part + (size_t)path * 16384;
  int c = threadIdx.x;
  float s = 0.f, q = 0.f;
  for (int b = 0; b < 32; b++) { s += pp[b * 512 + c]; q += pp[b * 512 + 256 + c]; }
  float mean = s * (1.f / 4096.f);
  float var  = q * (1.f / 4096.f) - mean * mean;
  float rstd = rsqrtf(var + 1e-5f);
  int r0 = rb * 16;
  int colOff = path * 256;
  for (int r = r0; r < r0 + 16; r++) {
    float v = (y[(size_t)r * EMB + c] - mean) * rstd;
    v = (v > 0.f) ? v : 0.2f * v;
    v = sanitize_f(v);
    f[(size_t)r * 512 + colOff + c] = v;
  }
}

// ---------------- classifier tail ----------------
__global__ __launch_bounds__(256) void final_softmax(const float* __restrict__ f1, const float* __restrict__ W2,
                                                     const float* __restrict__ b2, float* __restrict__ out) {
  int w = threadIdx.x >> 6, lane = threadIdx.x & 63;
  int row = blockIdx.x * 4 + w;
  const float* fr = f1 + (size_t)row * 128;
  float x0 = fr[lane], x1 = fr[lane + 64];
  float p0 = x0 * W2[lane]       + x1 * W2[64 + lane];
  float p1 = x0 * W2[128 + lane] + x1 * W2[192 + lane];
#pragma unroll
  for (int off = 32; off; off >>= 1) { p0 += __shfl_xor(p0, off); p1 += __shfl_xor(p1, off); }
  if (lane == 0) {
    float l0 = p0 + b2[0], l1 = p1 + b2[1];
    float mx = fmaxf(l0, l1);
    float e0 = __expf(l0 - mx), e1 = __expf(l1 - mx);
    float inv = 1.f / (e0 + e1);
    out[(size_t)row * 2 + 0] = l0;
    out[(size_t)row * 2 + 1] = l1;
    out[8192 + (size_t)row * 2 + 0] = e0 * inv;
    out[8192 + (size_t)row * 2 + 1] = e1 * inv;
  }
}

extern "C" void kernel_launch(void* const* d_in, const int* in_sizes, int n_in,
                              void* d_out, int out_size, void* d_ws, size_t ws_size,
                              hipStream_t stream) {
  const float* img   = (const float*)d_in[2];
  const int*   adj   = (const int*)d_in[3];
  const float* W_img = (const float*)d_in[4];  const float* b_img = (const float*)d_in[5];
  const float* W_qkv = (const float*)d_in[6];  const float* b_qkv = (const float*)d_in[7];
  const float* W_o   = (const float*)d_in[8];  const float* b_o   = (const float*)d_in[9];
  const float* Wq_o  = (const float*)d_in[10]; const float* bq_o  = (const float*)d_in[11];
  const float* Wk_o  = (const float*)d_in[12]; const float* bk_o  = (const float*)d_in[13];
  const float* Wv_o  = (const float*)d_in[14]; const float* bv_o  = (const float*)d_in[15];
  const float* Ws_o  = (const float*)d_in[16]; const float* bs_o  = (const float*)d_in[17];
  const float* Wq_a  = (const float*)d_in[18]; const float* bq_a  = (const float*)d_in[19];
  const float* Wk_a  = (const float*)d_in[20]; const float* bk_a  = (const float*)d_in[21];
  const float* Wv_a  = (const float*)d_in[22]; const float* bv_a  = (const float*)d_in[23];
  const float* Ws_a  = (const float*)d_in[24]; const float* bs_a  = (const float*)d_in[25];
  const float* W_c1  = (const float*)d_in[26]; const float* b_c1  = (const float*)d_in[27];
  const float* W_c2  = (const float*)d_in[28]; const float* b_c2  = (const float*)d_in[29];

  char* ws = (char*)d_ws;
  float* h     = (float*)(ws + 0);                    // 4 MB
  float* hattn = (float*)(ws + (4ull  << 20));        // 4 MB (qkb aliases during mha)
  float* qbO   = (float*)(ws + (8ull  << 20));        // 4 MB
  u16*   kbO   = (u16*)  (ws + (12ull << 20));        // 2 MB (f16)
  u16*   vbO   = (u16*)  (ws + (14ull << 20));        // 2 MB (bf16)
  float* qbA   = (float*)(ws + (16ull << 20));        // 4 MB
  u16*   kbA   = (u16*)  (ws + (20ull << 20));        // 2 MB (f16)
  u16*   vbA   = (u16*)  (ws + (22ull << 20));        // 2 MB (bf16)
  float* yO    = (float*)(ws + (24ull << 20));        // 4 MB (ymha aliases)
  float* yA    = (float*)(ws + (28ull << 20));        // 4 MB
  float* f     = (float*)(ws + (32ull << 20));        // 8 MB
  float* f1    = (float*)(ws + (40ull << 20));        // 2 MB (vtb aliases)
  int*   indptr= (int*)  (ws + (42ull << 20));
  int*   cursor= (int*)  (ws + (42ull << 20) + 20480);
  int*   esrc  = (int*)  (ws + (42ull << 20) + 40960);  // 1 MB (mspart aliases)
  float* part  = (float*)(ws + (42ull << 20) + 40960 + (1ull << 20)); // 128 KB

  u16*   qkb     = (u16*)hattn;      // 4 MB, dead until step 4
  u16*   vtb     = (u16*)f1;         // 2 MB, dead until step 8
  float* imgpart = qbO;              // 16 MB (ws+8..24M), free during step 1
  float* Opart   = qbO;              // 16 MB (ws+8..24M), free during mha
  float* mspart  = (float*)esrc;     // 512 KB, free during mha
  float* ymha    = yO;               // 4 MB, free until conv GEMM writes skip

  dim3 b256(256);

  // 1. h = img_feat @ W_img^T + b_img   (split-K x4)
  gemm_img_splitk<<<dim3(64, 4, 4), b256, 0, stream>>>(img, W_img, imgpart);
  gemm_img_reduce<<<1024, b256, 0, stream>>>(imgpart, b_img, h);
  // 2. qkv GEMM -> qkb (Q|K bf16), vtb (V^T bf16)
  {
    GArgs ga;
    for (int i = 0; i < 8; i++)
      ga.t[i]  = { h, W_qkv + (size_t)i * 64 * 256, b_qkv + i * 64, (float*)qkb, i * 64, 512, 1 };
    for (int i = 8; i < 12; i++)
      ga.t[i]  = { h, W_qkv + (size_t)i * 64 * 256, b_qkv + i * 64, (float*)vtb, (i - 8) * 64, 4096, 2 };
    gemm_mfma<0><<<dim3(64, 12), b256, 0, stream>>>(ga, 256);
  }
  // 3. causal MHA (split-K x4) -> ymha
  mha_mfma3<<<1024, b256, 0, stream>>>(qkb, vtb, Opart, mspart);
  mha_merge3<<<256, b256, 0, stream>>>(Opart, mspart, ymha);
  // 4. h_attn = sanitize(ymha @ W_o^T + b_o)
  {
    GArgs ga;
    for (int i = 0; i < 4; i++)
      ga.t[i] = { ymha, W_o + (size_t)i * 64 * 256, b_o + i * 64, hattn, i * 64, 256, 0 };
    gemm_mfma<1><<<dim3(64, 4), b256, 0, stream>>>(ga, 256);
  }
  // 5. CSR of video_adj_list grouped by dst
  zero_i32<<<16, b256, 0, stream>>>(cursor, NN);
  hist_dst<<<NE / 256, b256, 0, stream>>>(adj, cursor);
  scan4096<<<1, 1024, 0, stream>>>(cursor, indptr, cursor);
  scatter_edges<<<NE / 256, b256, 0, stream>>>(adj, cursor, esrc);

  // 6. both conv paths' q/k/v/skip in ONE dispatch (32 tiles); K in f16, V in bf16
  {
    const float* Wg[8] = { Wq_o, Wk_o, Wv_o, Ws_o, Wq_a, Wk_a, Wv_a, Ws_a };
    const float* bg[8] = { bq_o, bk_o, bv_o, bs_o, bq_a, bk_a, bv_a, bs_a };
    float*       og[8] = { qbO, (float*)kbO, (float*)vbO, yO, qbA, (float*)kbA, (float*)vbA, yA };
    const float* Ag[8] = { h, h, h, h, hattn, hattn, hattn, hattn };
    const int    bf[8] = { 0, 3, 1, 0, 0, 3, 1, 0 };
    GArgs ga;
    for (int i = 0; i < 32; i++) {
      int gdx = i >> 2, li = i & 3;
      ga.t[i] = { Ag[gdx], Wg[gdx] + (size_t)li * 64 * 256, bg[gdx] + li * 64, og[gdx], li * 64, 256, bf[gdx] };
    }
    gemm_mfma<0><<<dim3(64, 32), b256, 0, stream>>>(ga, 256);
  }
  // 7. both conv aggregations in ONE dispatch (wave-autonomous)
  conv_agg3<<<8192, b256, 0, stream>>>(qbO, qbA, kbO, kbA, vbO, vbA, indptr, esrc, yO, yA);
  // 8. instance norm both paths
  colstats_partial2<<<64, b256, 0, stream>>>(yO, yA, part);
  norm_apply2<<<512, b256, 0, stream>>>(yO, yA, part, f);
  // 9. f1 = lrelu(f @ W_c1^T + b_c1)
  {
    GArgs ga;
    for (int i = 0; i < 2; i++)
      ga.t[i] = { f, W_c1 + (size_t)i * 64 * 512, b_c1 + i * 64, f1, i * 64, 128, 0 };
    gemm_mfma<2><<<dim3(64, 2), b256, 0, stream>>>(ga, 512);
  }
  // 10. logits + softmax -> out
  final_softmax<<<NN / 4, b256, 0, stream>>>(f1, W_c2, b_c2, (float*)d_out);
}